// Round 6
// baseline (285.058 us; speedup 1.0000x reference)
//
#include <hip/hip_runtime.h>
#include <hip/hip_fp16.h>

// Problem constants (from reference)
#define N0C 4096
#define E0C 16384
#define N1C 1024
#define E1C 8192
#define HC 64
#define FINC 8
#define LATC 32
#define FC 67
#define E0T (E0C + N0C)
#define E1T (E1C + N1C)

typedef float f32x4 __attribute__((ext_vector_type(4)));
typedef _Float16 f16x8 __attribute__((ext_vector_type(8)));

// ---- k_prep: blocks [0,256): encoder + per-node t/d (level 0, 4 nodes/wave)
//              blocks [256,436): basis+w1 frag packing (fp16) + degree count
__global__ __launch_bounds__(256) void k_prep(
    const float* __restrict__ x, const float* __restrict__ l0w,
    const float* __restrict__ l0b, const float* __restrict__ posp,
    const float* __restrict__ c0w2, const float* __restrict__ c0b2,
    const float* __restrict__ c0w0, const float* __restrict__ c1w0,
    const float* __restrict__ c0w1, const float* __restrict__ c1w1,
    const int* __restrict__ ei0, const int* __restrict__ ei1,
    _Float16* __restrict__ bC0, _Float16* __restrict__ bS0,
    _Float16* __restrict__ bC1, _Float16* __restrict__ bS1,
    _Float16* __restrict__ w1f0, _Float16* __restrict__ w1f1,
    int* __restrict__ cnt, float* __restrict__ tN, float* __restrict__ dN) {
  if (blockIdx.x < 256) {
    __shared__ float w2s[64][69];  // pad 67->69
    __shared__ float xr[4][64];
    const int tid = threadIdx.x;
    const int wave = __builtin_amdgcn_readfirstlane(tid >> 6), lane = tid & 63;
    for (int idx = tid; idx < HC * FC; idx += 256)
      w2s[idx / FC][idx % FC] = c0w2[idx];
    __syncthreads();
#pragma unroll
    for (int i = 0; i < 4; ++i) {
      const int n = (blockIdx.x * 4 + wave) + i * 1024;
      float a = l0b[lane];
#pragma unroll
      for (int f = 0; f < FINC; ++f) a = fmaf(x[n * FINC + f], l0w[f * HC + lane], a);
      xr[wave][lane] = sinf(0.01f * a);
      __builtin_amdgcn_wave_barrier();
      const float px = posp[n * 3], py = posp[n * 3 + 1], pz = posp[n * 3 + 2];
      float tl = 0.f, ds = 0.f;
#pragma unroll 8
      for (int f = 0; f < HC; ++f) {
        float xv = xr[wave][f];
        tl = fmaf(xv, w2s[lane][f], tl);
        ds = fmaf(xv, c0b2[f], ds);
      }
      tl = fmaf(px, w2s[lane][64], fmaf(py, w2s[lane][65], fmaf(pz, w2s[lane][66], tl)));
      ds = fmaf(px, c0b2[64], fmaf(py, c0b2[65], fmaf(pz, c0b2[66], ds)));
      tN[n * HC + lane] = tl;
      if (lane == 0) dN[n] = ds;
      __builtin_amdgcn_wave_barrier();
    }
  } else {
    int id = (blockIdx.x - 256) * 256 + threadIdx.x;
    if (id < 8192) {  // basis frags: r=((ks*4+nt)*64+lane)*8+j
      int lvl = id >> 12, r = id & 4095;
      int fi = r >> 9, lane = (r >> 3) & 63, j = r & 7;
      int nt = fi & 3, ks = fi >> 2;
      int c = nt * 16 + (lane & 15);
      int h = ks * 32 + (lane >> 4) * 8 + j;
      const float* w = lvl ? c1w0 : c0w0;
      float s, cv;
      sincosf(0.1f * (float)c * w[3 * HC + h], &s, &cv);
      (lvl ? bC1 : bC0)[r] = (_Float16)cv;
      (lvl ? bS1 : bS0)[r] = (_Float16)s;
    } else if (id < 16384) {  // w1 frags (pre-scaled by 0.1)
      int r0 = id - 8192;
      int lvl = r0 >> 12, r = r0 & 4095;
      int fi = r >> 9, lane = (r >> 3) & 63, j = r & 7;
      int ms = fi & 3, ks = fi >> 2;
      int h = ks * 32 + (lane >> 4) * 8 + j;
      int kout = ms * 16 + (lane & 15);
      const float* w = lvl ? c1w1 : c0w1;
      (lvl ? w1f1 : w1f0)[r] = (_Float16)(0.1f * w[h * HC + kout]);
    } else if (id < 16384 + E0T + E1T) {  // degree
      int r = id - 16384;
      if (r < E0T) {
        int dst = (r < E0C) ? ei0[E0C + r] : (r - E0C);
        atomicAdd(cnt + dst, 1);
      } else {
        int e = r - E0T;
        int dst = (e < E1C) ? ei1[E1C + e] : (e - E1C);
        atomicAdd(cnt + N0C + dst, 1);
      }
    }
  }
}

// ---- CSR scan, shfl-based (block 0: level0, block 1: level1) ----------------
__global__ void k_scan(const int* __restrict__ cnt, int* __restrict__ rp0,
                       int* __restrict__ rp1) {
  __shared__ int wsum[16];
  const int b = blockIdx.x;
  const int n = b ? N1C : N0C;
  const int* c = cnt + (b ? N0C : 0);
  int* rp = b ? rp1 : rp0;
  const int tid = threadIdx.x;
  const int lane = tid & 63, wid = tid >> 6;
  const int per = n >> 10;
  int loc[4];
  int sum = 0;
  for (int j = 0; j < per; ++j) { loc[j] = c[tid * per + j]; sum += loc[j]; }
  int xv = sum;
#pragma unroll
  for (int off = 1; off < 64; off <<= 1) {
    int v = __shfl_up(xv, off, 64);
    if (lane >= off) xv += v;
  }
  if (lane == 63) wsum[wid] = xv;
  __syncthreads();
  if (wid == 0) {
    int w = (lane < 16) ? wsum[lane] : 0;
#pragma unroll
    for (int off = 1; off < 16; off <<= 1) {
      int v = __shfl_up(w, off, 64);
      if (lane >= off) w += v;
    }
    if (lane < 16) wsum[lane] = w;
  }
  __syncthreads();
  int prefix = wid ? wsum[wid - 1] : 0;
  int incl = xv + prefix;
  int base = incl - sum;
  for (int j = 0; j < per; ++j) { rp[tid * per + j] = base; base += loc[j]; }
  if (tid == 1023) rp[n] = incl;
}

// ---- CSR scatter (also emits inverse permutation) ---------------------------
__global__ void k_scatter(const int* __restrict__ ei0, const int* __restrict__ ei1,
                          const int* __restrict__ rp0, const int* __restrict__ rp1,
                          int* __restrict__ fill, int* __restrict__ eidx0,
                          int* __restrict__ eidx1, int* __restrict__ inv0,
                          int* __restrict__ inv1) {
  int id = blockIdx.x * blockDim.x + threadIdx.x;
  if (id < E0T) {
    int dst = (id < E0C) ? ei0[E0C + id] : (id - E0C);
    int p = rp0[dst] + atomicAdd(fill + dst, 1);
    eidx0[p] = id;
    inv0[id] = p;
  } else if (id < E0T + E1T) {
    int e = id - E0T;
    int dst = (e < E1C) ? ei1[E1C + e] : (e - E1C);
    int p = rp1[dst] + atomicAdd(fill + N0C + dst, 1);
    eidx1[p] = e;
    inv1[e] = p;
  }
}

// ---- k_conv: persistent edge-parallel, pipelined; msg stored in CSR order ---
__global__ __launch_bounds__(256, 4) void k_conv(
    const int* __restrict__ ei, int E, int eTot,
    const float* __restrict__ posp,
    const float* __restrict__ tN, const float* __restrict__ dN,
    const float* __restrict__ kw0, const float* __restrict__ kb0,
    const _Float16* __restrict__ bC, const _Float16* __restrict__ bS,
    const _Float16* __restrict__ w1f, const float* __restrict__ b1,
    const int* __restrict__ inv, float* __restrict__ msg) {
  __shared__ __attribute__((aligned(16))) _Float16 bCs[4096], bSs[4096];
  __shared__ __attribute__((aligned(16))) _Float16 scS[4][2][64], scC[4][2][64];
  const int tid = threadIdx.x;
  const int wave = __builtin_amdgcn_readfirstlane(tid >> 6), lane = tid & 63;
  const int q = lane >> 4;
  for (int idx = tid; idx < 512; idx += 256) {
    ((f16x8*)bCs)[idx] = ((const f16x8*)bC)[idx];
    ((f16x8*)bSs)[idx] = ((const f16x8*)bS)[idx];
  }
  f16x8 w1r[8];
#pragma unroll
  for (int f = 0; f < 8; ++f) w1r[f] = *(const f16x8*)(w1f + ((f << 6) + lane) * 8);
  f32x4 bbq[4];  // accumulator init = 0.1*b1[k]
#pragma unroll
  for (int ms = 0; ms < 4; ++ms) {
    f32x4 t = *(const f32x4*)(b1 + ms * 16 + q * 4);
    bbq[ms] = t * 0.1f;
  }
  const float kb0v = kb0[lane];
  const float kw0x = kw0[lane], kw0y = kw0[HC + lane], kw0z = kw0[2 * HC + lane];
  __syncthreads();

  const int nW = gridDim.x * 4;
  int e = blockIdx.x * 4 + wave;
  if (e >= eTot) return;

  auto stg = [&](int ee, int& sN, float& sv, float& cv, float& dv) {
    int s, d2;
    if (ee < E) { s = ei[ee]; d2 = ei[E + ee]; } else { s = ee - E; d2 = s; }
    sN = s;
    const float px = posp[s * 3], py = posp[s * 3 + 1], pz = posp[s * 3 + 2];
    const float rx = posp[d2 * 3] - px;
    const float ry = posp[d2 * 3 + 1] - py;
    const float rz = posp[d2 * 3 + 2] - pz;
    float f0 = 0.f, f1 = 0.f, f2 = 0.f;
    if (!(rx == 0.f && ry == 0.f && rz == 0.f)) {
      const float PI_F = 3.14159265358979323846f;
      float rho = sqrtf(rx * rx + ry * ry + rz * rz);
      float th = atan2f(ry, rx);
      float ratio = fminf(1.f, fmaxf(-1.f, rz / rho));
      float ph = asinf(ratio);
      f0 = rho; f1 = th / PI_F; f2 = ph / PI_F;
    }
    float base = fmaf(f0, kw0x, fmaf(f1, kw0y, fmaf(f2, kw0z, kb0v)));
    sincosf(0.1f * base, &sv, &cv);
    dv = dN[s];
  };

  int s0;
  float sv0, cv0, dv0;
  stg(e, s0, sv0, cv0, dv0);
  int buf = 0;
  scS[wave][0][lane] = (_Float16)sv0;
  scC[wave][0][lane] = (_Float16)cv0;
  __builtin_amdgcn_wave_barrier();

  while (true) {
    const int en = e + nW;
    const bool more = en < eTot;
    // prefetch t-row + inv for current edge
    f32x4 tr[4];
    {
      const float* trp = tN + (size_t)s0 * HC;
#pragma unroll
      for (int ms = 0; ms < 4; ++ms) tr[ms] = *(const f32x4*)(trp + ms * 16 + q * 4);
    }
    const int ip = inv[e];
    // stage next edge (loads + trig) before compute of current
    int s1 = 0;
    float sv1 = 0.f, cv1 = 0.f, dv1 = 0.f;
    if (more) {
      stg(en, s1, sv1, cv1, dv1);
      scS[wave][buf ^ 1][lane] = (_Float16)sv1;
      scC[wave][buf ^ 1][lane] = (_Float16)cv1;
    }
    __builtin_amdgcn_wave_barrier();

    f32x4 acc[4][4];
#pragma unroll
    for (int ms = 0; ms < 4; ++ms)
#pragma unroll
      for (int nt = 0; nt < 4; ++nt) acc[ms][nt] = bbq[ms];
#pragma unroll
    for (int ks = 0; ks < 2; ++ks) {
      f16x8 sv8 = *(const f16x8*)&scS[wave][buf][ks * 32 + q * 8];
      f16x8 cv8 = *(const f16x8*)&scC[wave][buf][ks * 32 + q * 8];
      f16x8 bf[4];
#pragma unroll
      for (int nt = 0; nt < 4; ++nt) {
        f16x8 cb = *(const f16x8*)&bCs[((ks * 4 + nt) * 64 + lane) * 8];
        f16x8 sb = *(const f16x8*)&bSs[((ks * 4 + nt) * 64 + lane) * 8];
        bf[nt] = sv8 * cb + cv8 * sb;
      }
#pragma unroll
      for (int ms = 0; ms < 4; ++ms)
#pragma unroll
        for (int nt = 0; nt < 4; ++nt)
          acc[ms][nt] = __builtin_amdgcn_mfma_f32_16x16x32_f16(
              w1r[ks * 4 + ms], bf[nt], acc[ms][nt], 0, 0, 0);
    }

    // epilogue: reg r of acc[ms][nt] = 0.1*(z+b1) at [k=ms*16+q*4+r][c=nt*16+m]
    float snt0 = 0.f, snt1 = 0.f, snt2 = 0.f, snt3 = 0.f;
#pragma unroll
    for (int ms = 0; ms < 4; ++ms) {
#pragma unroll
      for (int r = 0; r < 4; ++r) {
        float tt = tr[ms][r];
        snt0 = fmaf(__sinf(acc[ms][0][r]), tt, snt0);
        snt1 = fmaf(__sinf(acc[ms][1][r]), tt, snt1);
        snt2 = fmaf(__sinf(acc[ms][2][r]), tt, snt2);
        snt3 = fmaf(__sinf(acc[ms][3][r]), tt, snt3);
      }
    }
    snt0 += __shfl_xor(snt0, 16, 64); snt0 += __shfl_xor(snt0, 32, 64);
    snt1 += __shfl_xor(snt1, 16, 64); snt1 += __shfl_xor(snt1, 32, 64);
    snt2 += __shfl_xor(snt2, 16, 64); snt2 += __shfl_xor(snt2, 32, 64);
    snt3 += __shfl_xor(snt3, 16, 64); snt3 += __shfl_xor(snt3, 32, 64);
    float val = (q == 0) ? snt0 : (q == 1) ? snt1 : (q == 2) ? snt2 : snt3;
    msg[(size_t)ip * HC + lane] = val + dv0;

    if (!more) break;
    e = en; s0 = s1; dv0 = dv1; buf ^= 1;
  }
}

// ---- CSR segment-sum (contiguous msg) + sin(0.01*(sum+bias)) ----------------
__global__ void k_reduce0(const float* __restrict__ msg, const int* __restrict__ rp,
                          const float* __restrict__ bias, float* __restrict__ hc) {
  const int wave = threadIdx.x >> 6, lane = threadIdx.x & 63;
  const int n = blockIdx.x * 4 + wave;
  const int j0 = rp[n], j1 = rp[n + 1];
  const float* p = msg + (size_t)j0 * HC + lane;
  const int m = j1 - j0;
  float a0 = 0.f, a1 = 0.f;
  int j = 0;
  for (; j + 1 < m; j += 2) {
    a0 += p[(size_t)j * HC];
    a1 += p[(size_t)(j + 1) * HC];
  }
  if (j < m) a0 += p[(size_t)j * HC];
  hc[(size_t)n * HC + lane] = sinf(0.01f * (a0 + a1 + bias[lane]));
}

// ---- k_pool1: CSR max over kept nodes + per-node t/d for level 1 ------------
__global__ void k_pool1(const float* __restrict__ hc0, const int* __restrict__ eidx,
                        const int* __restrict__ rp, const int* __restrict__ ei,
                        const int* __restrict__ keep, const float* __restrict__ ppos,
                        const float* __restrict__ c1w2, const float* __restrict__ c1b2,
                        float* __restrict__ tN, float* __restrict__ dN) {
  __shared__ float w2s[64][69];
  __shared__ float xr[4][64];
  const int tid = threadIdx.x;
  const int wave = __builtin_amdgcn_readfirstlane(tid >> 6), lane = tid & 63;
  for (int idx = tid; idx < HC * FC; idx += 256)
    w2s[idx / FC][idx % FC] = c1w2[idx];
  const int i = blockIdx.x * 4 + wave;
  int n = keep[i];
  int j0 = rp[n], j1 = rp[n + 1];
  float m = -INFINITY;
  for (int j = j0; j < j1; ++j) {
    int e = eidx[j];
    int src = (e < E0C) ? ei[e] : (e - E0C);
    m = fmaxf(m, hc0[(size_t)src * HC + lane]);
  }
  xr[wave][lane] = m;
  __syncthreads();
  const float px = ppos[i * 3], py = ppos[i * 3 + 1], pz = ppos[i * 3 + 2];
  float tl = 0.f, ds = 0.f;
#pragma unroll 8
  for (int f = 0; f < HC; ++f) {
    float xv = xr[wave][f];
    tl = fmaf(xv, w2s[lane][f], tl);
    ds = fmaf(xv, c1b2[f], ds);
  }
  tl = fmaf(px, w2s[lane][64], fmaf(py, w2s[lane][65], fmaf(pz, w2s[lane][66], tl)));
  ds = fmaf(px, c1b2[64], fmaf(py, c1b2[65], fmaf(pz, c1b2[66], ds)));
  tN[i * HC + lane] = tl;
  if (lane == 0) dN[i] = ds;
}

// ---- reduce level-1 (contiguous msg) + final linear + sin -------------------
__global__ void k_reduce1f(const float* __restrict__ msg, const int* __restrict__ rp,
                           const float* __restrict__ bias, const float* __restrict__ l1w,
                           const float* __restrict__ l1b, float* __restrict__ outp) {
  __shared__ float hr[4][64];
  const int wave = threadIdx.x >> 6, lane = threadIdx.x & 63;
  const int node = blockIdx.x * 4 + wave;
  const int j0 = rp[node], j1 = rp[node + 1];
  const float* p = msg + (size_t)j0 * HC + lane;
  const int m = j1 - j0;
  float a0 = 0.f, a1 = 0.f;
  int j = 0;
  for (; j + 1 < m; j += 2) {
    a0 += p[(size_t)j * HC];
    a1 += p[(size_t)(j + 1) * HC];
  }
  if (j < m) a0 += p[(size_t)j * HC];
  hr[wave][lane] = sinf(0.01f * (a0 + a1 + bias[lane]));
  __syncthreads();
  if (lane < LATC) {
    const float* h = hr[wave];
    float o = l1b[lane];
#pragma unroll 8
    for (int c = 0; c < HC; ++c) o = fmaf(h[c], l1w[c * LATC + lane], o);
    outp[node * LATC + lane] = sinf(0.01f * o);
  }
}

extern "C" void kernel_launch(void* const* d_in, const int* in_sizes, int n_in,
                              void* d_out, int out_size, void* d_ws, size_t ws_size,
                              hipStream_t stream) {
  (void)in_sizes; (void)n_in; (void)out_size; (void)ws_size;
  const float* x    = (const float*)d_in[0];
  const float* pos  = (const float*)d_in[1];
  const int*   ei   = (const int*)d_in[2];
  const int*   pei  = (const int*)d_in[3];
  const float* ppos = (const float*)d_in[4];
  const int*   keep = (const int*)d_in[5];
  const float* l0w  = (const float*)d_in[6];
  const float* l0b  = (const float*)d_in[7];
  const float* l1w  = (const float*)d_in[8];
  const float* l1b  = (const float*)d_in[9];
  const float* c0w0 = (const float*)d_in[10];
  const float* c0b0 = (const float*)d_in[11];
  const float* c0w1 = (const float*)d_in[12];
  const float* c0b1 = (const float*)d_in[13];
  const float* c0w2 = (const float*)d_in[14];
  const float* c0b2 = (const float*)d_in[15];
  const float* c0bias = (const float*)d_in[16];
  const float* c1w0 = (const float*)d_in[17];
  const float* c1b0 = (const float*)d_in[18];
  const float* c1w1 = (const float*)d_in[19];
  const float* c1b1 = (const float*)d_in[20];
  const float* c1w2 = (const float*)d_in[21];
  const float* c1b2 = (const float*)d_in[22];
  const float* c1bias = (const float*)d_in[23];
  float* outp = (float*)d_out;

  char* p = (char*)d_ws;
  auto carve = [&](size_t bytes) -> char* {
    char* r = p;
    p += (bytes + 255) & ~(size_t)255;
    return r;
  };
  float* hc0  = (float*)carve((size_t)N0C * HC * 4);
  float* tN0  = (float*)carve((size_t)N0C * HC * 4);
  float* dN0  = (float*)carve((size_t)N0C * 4);
  float* tN1  = (float*)carve((size_t)N1C * HC * 4);
  float* dN1  = (float*)carve((size_t)N1C * 4);
  _Float16* bC0  = (_Float16*)carve(4096 * 2);
  _Float16* bS0  = (_Float16*)carve(4096 * 2);
  _Float16* bC1  = (_Float16*)carve(4096 * 2);
  _Float16* bS1  = (_Float16*)carve(4096 * 2);
  _Float16* w1f0 = (_Float16*)carve(4096 * 2);
  _Float16* w1f1 = (_Float16*)carve(4096 * 2);
  int* cnt  = (int*)carve((size_t)(N0C + N1C) * 4);  // cnt+fill contiguous
  int* fill = (int*)carve((size_t)(N0C + N1C) * 4);
  int* rp0 = (int*)carve((size_t)(N0C + 1) * 4);
  int* rp1 = (int*)carve((size_t)(N1C + 1) * 4);
  int* eidx0 = (int*)carve((size_t)E0T * 4);
  int* eidx1 = (int*)carve((size_t)E1T * 4);
  int* inv0  = (int*)carve((size_t)E0T * 4);
  int* inv1  = (int*)carve((size_t)E1T * 4);
  float* msg = (float*)carve((size_t)E0T * HC * 4);  // reused for level 1

  hipMemsetAsync(cnt, 0, (size_t)(N0C + N1C) * 4 * 2, stream);

  k_prep<<<256 + 180, 256, 0, stream>>>(x, l0w, l0b, pos, c0w2, c0b2,
                                        c0w0, c1w0, c0w1, c1w1, ei, pei,
                                        bC0, bS0, bC1, bS1, w1f0, w1f1,
                                        cnt, tN0, dN0);
  k_scan<<<2, 1024, 0, stream>>>(cnt, rp0, rp1);
  k_scatter<<<(E0T + E1T + 255) / 256, 256, 0, stream>>>(ei, pei, rp0, rp1, fill,
                                                         eidx0, eidx1, inv0, inv1);
  k_conv<<<1024, 256, 0, stream>>>(ei, E0C, E0T, pos, tN0, dN0, c0w0, c0b0,
                                   bC0, bS0, w1f0, c0b1, inv0, msg);
  k_reduce0<<<N0C / 4, 256, 0, stream>>>(msg, rp0, c0bias, hc0);
  k_pool1<<<N1C / 4, 256, 0, stream>>>(hc0, eidx0, rp0, ei, keep, ppos,
                                       c1w2, c1b2, tN1, dN1);
  k_conv<<<512, 256, 0, stream>>>(pei, E1C, E1T, ppos, tN1, dN1, c1w0, c1b0,
                                  bC1, bS1, w1f1, c1b1, inv1, msg);
  k_reduce1f<<<N1C / 4, 256, 0, stream>>>(msg, rp1, c1bias, l1w, l1b, outp);
}

// Round 7
// 180.940 us; speedup vs baseline: 1.5754x; 1.5754x over previous
//
#include <hip/hip_runtime.h>
#include <hip/hip_fp16.h>

// Problem constants (from reference)
#define N0C 4096
#define E0C 16384
#define N1C 1024
#define E1C 8192
#define HC 64
#define FINC 8
#define LATC 32
#define FC 67
#define E0T (E0C + N0C)
#define E1T (E1C + N1C)

typedef float f32x4 __attribute__((ext_vector_type(4)));
typedef _Float16 f16x8 __attribute__((ext_vector_type(8)));

// ---- k_prep: blocks [0,256): encoder + per-node t/d (level 0, 4 nodes/wave)
//              blocks [256,436): basis+w1 frag packing (fp16) + degree count
__global__ __launch_bounds__(256) void k_prep(
    const float* __restrict__ x, const float* __restrict__ l0w,
    const float* __restrict__ l0b, const float* __restrict__ posp,
    const float* __restrict__ c0w2, const float* __restrict__ c0b2,
    const float* __restrict__ c0w0, const float* __restrict__ c1w0,
    const float* __restrict__ c0w1, const float* __restrict__ c1w1,
    const int* __restrict__ ei0, const int* __restrict__ ei1,
    _Float16* __restrict__ bC0, _Float16* __restrict__ bS0,
    _Float16* __restrict__ bC1, _Float16* __restrict__ bS1,
    _Float16* __restrict__ w1f0, _Float16* __restrict__ w1f1,
    int* __restrict__ cnt, float* __restrict__ tN, float* __restrict__ dN) {
  if (blockIdx.x < 256) {
    __shared__ float w2s[64][69];  // pad 67->69
    __shared__ float xr[4][64];
    const int tid = threadIdx.x;
    const int wave = __builtin_amdgcn_readfirstlane(tid >> 6), lane = tid & 63;
    for (int idx = tid; idx < HC * FC; idx += 256)
      w2s[idx / FC][idx % FC] = c0w2[idx];
    __syncthreads();
#pragma unroll
    for (int i = 0; i < 4; ++i) {
      const int n = (blockIdx.x * 4 + wave) + i * 1024;
      float a = l0b[lane];
#pragma unroll
      for (int f = 0; f < FINC; ++f) a = fmaf(x[n * FINC + f], l0w[f * HC + lane], a);
      xr[wave][lane] = sinf(0.01f * a);
      __builtin_amdgcn_wave_barrier();
      const float px = posp[n * 3], py = posp[n * 3 + 1], pz = posp[n * 3 + 2];
      float tl = 0.f, ds = 0.f;
#pragma unroll 8
      for (int f = 0; f < HC; ++f) {
        float xv = xr[wave][f];
        tl = fmaf(xv, w2s[lane][f], tl);
        ds = fmaf(xv, c0b2[f], ds);
      }
      tl = fmaf(px, w2s[lane][64], fmaf(py, w2s[lane][65], fmaf(pz, w2s[lane][66], tl)));
      ds = fmaf(px, c0b2[64], fmaf(py, c0b2[65], fmaf(pz, c0b2[66], ds)));
      tN[n * HC + lane] = tl;
      if (lane == 0) dN[n] = ds;
      __builtin_amdgcn_wave_barrier();
    }
  } else {
    int id = (blockIdx.x - 256) * 256 + threadIdx.x;
    if (id < 8192) {  // basis frags: r=((ks*4+nt)*64+lane)*8+j
      int lvl = id >> 12, r = id & 4095;
      int fi = r >> 9, lane = (r >> 3) & 63, j = r & 7;
      int nt = fi & 3, ks = fi >> 2;
      int c = nt * 16 + (lane & 15);
      int h = ks * 32 + (lane >> 4) * 8 + j;
      const float* w = lvl ? c1w0 : c0w0;
      float s, cv;
      sincosf(0.1f * (float)c * w[3 * HC + h], &s, &cv);
      (lvl ? bC1 : bC0)[r] = (_Float16)cv;
      (lvl ? bS1 : bS0)[r] = (_Float16)s;
    } else if (id < 16384) {  // w1 frags (pre-scaled by 0.1)
      int r0 = id - 8192;
      int lvl = r0 >> 12, r = r0 & 4095;
      int fi = r >> 9, lane = (r >> 3) & 63, j = r & 7;
      int ms = fi & 3, ks = fi >> 2;
      int h = ks * 32 + (lane >> 4) * 8 + j;
      int kout = ms * 16 + (lane & 15);
      const float* w = lvl ? c1w1 : c0w1;
      (lvl ? w1f1 : w1f0)[r] = (_Float16)(0.1f * w[h * HC + kout]);
    } else if (id < 16384 + E0T + E1T) {  // degree
      int r = id - 16384;
      if (r < E0T) {
        int dst = (r < E0C) ? ei0[E0C + r] : (r - E0C);
        atomicAdd(cnt + dst, 1);
      } else {
        int e = r - E0T;
        int dst = (e < E1C) ? ei1[E1C + e] : (e - E1C);
        atomicAdd(cnt + N0C + dst, 1);
      }
    }
  }
}

// ---- CSR scan, shfl-based (block 0: level0, block 1: level1) ----------------
__global__ void k_scan(const int* __restrict__ cnt, int* __restrict__ rp0,
                       int* __restrict__ rp1) {
  __shared__ int wsum[16];
  const int b = blockIdx.x;
  const int n = b ? N1C : N0C;
  const int* c = cnt + (b ? N0C : 0);
  int* rp = b ? rp1 : rp0;
  const int tid = threadIdx.x;
  const int lane = tid & 63, wid = tid >> 6;
  const int per = n >> 10;
  int loc[4];
  int sum = 0;
  for (int j = 0; j < per; ++j) { loc[j] = c[tid * per + j]; sum += loc[j]; }
  int xv = sum;
#pragma unroll
  for (int off = 1; off < 64; off <<= 1) {
    int v = __shfl_up(xv, off, 64);
    if (lane >= off) xv += v;
  }
  if (lane == 63) wsum[wid] = xv;
  __syncthreads();
  if (wid == 0) {
    int w = (lane < 16) ? wsum[lane] : 0;
#pragma unroll
    for (int off = 1; off < 16; off <<= 1) {
      int v = __shfl_up(w, off, 64);
      if (lane >= off) w += v;
    }
    if (lane < 16) wsum[lane] = w;
  }
  __syncthreads();
  int prefix = wid ? wsum[wid - 1] : 0;
  int incl = xv + prefix;
  int base = incl - sum;
  for (int j = 0; j < per; ++j) { rp[tid * per + j] = base; base += loc[j]; }
  if (tid == 1023) rp[n] = incl;
}

// ---- CSR scatter (also emits inverse permutation) ---------------------------
__global__ void k_scatter(const int* __restrict__ ei0, const int* __restrict__ ei1,
                          const int* __restrict__ rp0, const int* __restrict__ rp1,
                          int* __restrict__ fill, int* __restrict__ eidx0,
                          int* __restrict__ eidx1, int* __restrict__ inv0,
                          int* __restrict__ inv1) {
  int id = blockIdx.x * blockDim.x + threadIdx.x;
  if (id < E0T) {
    int dst = (id < E0C) ? ei0[E0C + id] : (id - E0C);
    int p = rp0[dst] + atomicAdd(fill + dst, 1);
    eidx0[p] = id;
    inv0[id] = p;
  } else if (id < E0T + E1T) {
    int e = id - E0T;
    int dst = (e < E1C) ? ei1[E1C + e] : (e - E1C);
    int p = rp1[dst] + atomicAdd(fill + N0C + dst, 1);
    eidx1[p] = e;
    inv1[e] = p;
  }
}

// ---- k_conv: persistent edge-parallel, pipelined; msg stored in CSR order ---
// NOTE: min-waves=3 (84-128 VGPR, no spill). (256,4) forced VGPR=64 and spilled
// the accumulators to scratch -> 208MB HBM fetch/launch (R6 regression).
__global__ __launch_bounds__(256, 3) void k_conv(
    const int* __restrict__ ei, int E, int eTot,
    const float* __restrict__ posp,
    const float* __restrict__ tN, const float* __restrict__ dN,
    const float* __restrict__ kw0, const float* __restrict__ kb0,
    const _Float16* __restrict__ bC, const _Float16* __restrict__ bS,
    const _Float16* __restrict__ w1f, const float* __restrict__ b1,
    const int* __restrict__ inv, float* __restrict__ msg) {
  __shared__ __attribute__((aligned(16))) _Float16 bCs[4096], bSs[4096];
  __shared__ __attribute__((aligned(16))) _Float16 scS[4][2][64], scC[4][2][64];
  const int tid = threadIdx.x;
  const int wave = __builtin_amdgcn_readfirstlane(tid >> 6), lane = tid & 63;
  const int q = lane >> 4;
  for (int idx = tid; idx < 512; idx += 256) {
    ((f16x8*)bCs)[idx] = ((const f16x8*)bC)[idx];
    ((f16x8*)bSs)[idx] = ((const f16x8*)bS)[idx];
  }
  f16x8 w1r[8];
#pragma unroll
  for (int f = 0; f < 8; ++f) w1r[f] = *(const f16x8*)(w1f + ((f << 6) + lane) * 8);
  f32x4 bbq[4];  // accumulator init = 0.1*b1[k]
#pragma unroll
  for (int ms = 0; ms < 4; ++ms) {
    f32x4 t = *(const f32x4*)(b1 + ms * 16 + q * 4);
    bbq[ms] = t * 0.1f;
  }
  const float kb0v = kb0[lane];
  const float kw0x = kw0[lane], kw0y = kw0[HC + lane], kw0z = kw0[2 * HC + lane];
  __syncthreads();

  const int nW = gridDim.x * 4;
  int e = blockIdx.x * 4 + wave;
  if (e >= eTot) return;

  auto stg = [&](int ee, int& sN, float& sv, float& cv, float& dv) {
    int s, d2;
    if (ee < E) { s = ei[ee]; d2 = ei[E + ee]; } else { s = ee - E; d2 = s; }
    sN = s;
    const float px = posp[s * 3], py = posp[s * 3 + 1], pz = posp[s * 3 + 2];
    const float rx = posp[d2 * 3] - px;
    const float ry = posp[d2 * 3 + 1] - py;
    const float rz = posp[d2 * 3 + 2] - pz;
    float f0 = 0.f, f1 = 0.f, f2 = 0.f;
    if (!(rx == 0.f && ry == 0.f && rz == 0.f)) {
      const float PI_F = 3.14159265358979323846f;
      float rho = sqrtf(rx * rx + ry * ry + rz * rz);
      float th = atan2f(ry, rx);
      float ratio = fminf(1.f, fmaxf(-1.f, rz / rho));
      float ph = asinf(ratio);
      f0 = rho; f1 = th / PI_F; f2 = ph / PI_F;
    }
    float base = fmaf(f0, kw0x, fmaf(f1, kw0y, fmaf(f2, kw0z, kb0v)));
    sincosf(0.1f * base, &sv, &cv);
    dv = dN[s];
  };

  int s0;
  float sv0, cv0, dv0;
  stg(e, s0, sv0, cv0, dv0);
  int buf = 0;
  scS[wave][0][lane] = (_Float16)sv0;
  scC[wave][0][lane] = (_Float16)cv0;
  __builtin_amdgcn_wave_barrier();

  while (true) {
    const int en = e + nW;
    const bool more = en < eTot;
    // prefetch t-row + inv for current edge
    f32x4 tr[4];
    {
      const float* trp = tN + (size_t)s0 * HC;
#pragma unroll
      for (int ms = 0; ms < 4; ++ms) tr[ms] = *(const f32x4*)(trp + ms * 16 + q * 4);
    }
    const int ip = inv[e];
    // stage next edge (loads + trig) before compute of current
    int s1 = 0;
    float sv1 = 0.f, cv1 = 0.f, dv1 = 0.f;
    if (more) {
      stg(en, s1, sv1, cv1, dv1);
      scS[wave][buf ^ 1][lane] = (_Float16)sv1;
      scC[wave][buf ^ 1][lane] = (_Float16)cv1;
    }
    __builtin_amdgcn_wave_barrier();

    f32x4 acc[4][4];
#pragma unroll
    for (int ms = 0; ms < 4; ++ms)
#pragma unroll
      for (int nt = 0; nt < 4; ++nt) acc[ms][nt] = bbq[ms];
#pragma unroll
    for (int ks = 0; ks < 2; ++ks) {
      f16x8 sv8 = *(const f16x8*)&scS[wave][buf][ks * 32 + q * 8];
      f16x8 cv8 = *(const f16x8*)&scC[wave][buf][ks * 32 + q * 8];
      f16x8 bf[4];
#pragma unroll
      for (int nt = 0; nt < 4; ++nt) {
        f16x8 cb = *(const f16x8*)&bCs[((ks * 4 + nt) * 64 + lane) * 8];
        f16x8 sb = *(const f16x8*)&bSs[((ks * 4 + nt) * 64 + lane) * 8];
        bf[nt] = sv8 * cb + cv8 * sb;
      }
#pragma unroll
      for (int ms = 0; ms < 4; ++ms)
#pragma unroll
        for (int nt = 0; nt < 4; ++nt)
          acc[ms][nt] = __builtin_amdgcn_mfma_f32_16x16x32_f16(
              w1r[ks * 4 + ms], bf[nt], acc[ms][nt], 0, 0, 0);
    }

    // epilogue: reg r of acc[ms][nt] = 0.1*(z+b1) at [k=ms*16+q*4+r][c=nt*16+m]
    float snt0 = 0.f, snt1 = 0.f, snt2 = 0.f, snt3 = 0.f;
#pragma unroll
    for (int ms = 0; ms < 4; ++ms) {
#pragma unroll
      for (int r = 0; r < 4; ++r) {
        float tt = tr[ms][r];
        snt0 = fmaf(__sinf(acc[ms][0][r]), tt, snt0);
        snt1 = fmaf(__sinf(acc[ms][1][r]), tt, snt1);
        snt2 = fmaf(__sinf(acc[ms][2][r]), tt, snt2);
        snt3 = fmaf(__sinf(acc[ms][3][r]), tt, snt3);
      }
    }
    snt0 += __shfl_xor(snt0, 16, 64); snt0 += __shfl_xor(snt0, 32, 64);
    snt1 += __shfl_xor(snt1, 16, 64); snt1 += __shfl_xor(snt1, 32, 64);
    snt2 += __shfl_xor(snt2, 16, 64); snt2 += __shfl_xor(snt2, 32, 64);
    snt3 += __shfl_xor(snt3, 16, 64); snt3 += __shfl_xor(snt3, 32, 64);
    float val = (q == 0) ? snt0 : (q == 1) ? snt1 : (q == 2) ? snt2 : snt3;
    msg[(size_t)ip * HC + lane] = val + dv0;

    if (!more) break;
    e = en; s0 = s1; dv0 = dv1; buf ^= 1;
  }
}

// ---- CSR segment-sum (contiguous msg) + sin(0.01*(sum+bias)) ----------------
__global__ void k_reduce0(const float* __restrict__ msg, const int* __restrict__ rp,
                          const float* __restrict__ bias, float* __restrict__ hc) {
  const int wave = threadIdx.x >> 6, lane = threadIdx.x & 63;
  const int n = blockIdx.x * 4 + wave;
  const int j0 = rp[n], j1 = rp[n + 1];
  const float* p = msg + (size_t)j0 * HC + lane;
  const int m = j1 - j0;
  float a0 = 0.f, a1 = 0.f;
  int j = 0;
  for (; j + 1 < m; j += 2) {
    a0 += p[(size_t)j * HC];
    a1 += p[(size_t)(j + 1) * HC];
  }
  if (j < m) a0 += p[(size_t)j * HC];
  hc[(size_t)n * HC + lane] = sinf(0.01f * (a0 + a1 + bias[lane]));
}

// ---- k_pool1: CSR max over kept nodes + per-node t/d for level 1 ------------
__global__ void k_pool1(const float* __restrict__ hc0, const int* __restrict__ eidx,
                        const int* __restrict__ rp, const int* __restrict__ ei,
                        const int* __restrict__ keep, const float* __restrict__ ppos,
                        const float* __restrict__ c1w2, const float* __restrict__ c1b2,
                        float* __restrict__ tN, float* __restrict__ dN) {
  __shared__ float w2s[64][69];
  __shared__ float xr[4][64];
  const int tid = threadIdx.x;
  const int wave = __builtin_amdgcn_readfirstlane(tid >> 6), lane = tid & 63;
  for (int idx = tid; idx < HC * FC; idx += 256)
    w2s[idx / FC][idx % FC] = c1w2[idx];
  const int i = blockIdx.x * 4 + wave;
  int n = keep[i];
  int j0 = rp[n], j1 = rp[n + 1];
  float m = -INFINITY;
  for (int j = j0; j < j1; ++j) {
    int e = eidx[j];
    int src = (e < E0C) ? ei[e] : (e - E0C);
    m = fmaxf(m, hc0[(size_t)src * HC + lane]);
  }
  xr[wave][lane] = m;
  __syncthreads();
  const float px = ppos[i * 3], py = ppos[i * 3 + 1], pz = ppos[i * 3 + 2];
  float tl = 0.f, ds = 0.f;
#pragma unroll 8
  for (int f = 0; f < HC; ++f) {
    float xv = xr[wave][f];
    tl = fmaf(xv, w2s[lane][f], tl);
    ds = fmaf(xv, c1b2[f], ds);
  }
  tl = fmaf(px, w2s[lane][64], fmaf(py, w2s[lane][65], fmaf(pz, w2s[lane][66], tl)));
  ds = fmaf(px, c1b2[64], fmaf(py, c1b2[65], fmaf(pz, c1b2[66], ds)));
  tN[i * HC + lane] = tl;
  if (lane == 0) dN[i] = ds;
}

// ---- reduce level-1 (contiguous msg) + final linear + sin -------------------
__global__ void k_reduce1f(const float* __restrict__ msg, const int* __restrict__ rp,
                           const float* __restrict__ bias, const float* __restrict__ l1w,
                           const float* __restrict__ l1b, float* __restrict__ outp) {
  __shared__ float hr[4][64];
  const int wave = threadIdx.x >> 6, lane = threadIdx.x & 63;
  const int node = blockIdx.x * 4 + wave;
  const int j0 = rp[node], j1 = rp[node + 1];
  const float* p = msg + (size_t)j0 * HC + lane;
  const int m = j1 - j0;
  float a0 = 0.f, a1 = 0.f;
  int j = 0;
  for (; j + 1 < m; j += 2) {
    a0 += p[(size_t)j * HC];
    a1 += p[(size_t)(j + 1) * HC];
  }
  if (j < m) a0 += p[(size_t)j * HC];
  hr[wave][lane] = sinf(0.01f * (a0 + a1 + bias[lane]));
  __syncthreads();
  if (lane < LATC) {
    const float* h = hr[wave];
    float o = l1b[lane];
#pragma unroll 8
    for (int c = 0; c < HC; ++c) o = fmaf(h[c], l1w[c * LATC + lane], o);
    outp[node * LATC + lane] = sinf(0.01f * o);
  }
}

extern "C" void kernel_launch(void* const* d_in, const int* in_sizes, int n_in,
                              void* d_out, int out_size, void* d_ws, size_t ws_size,
                              hipStream_t stream) {
  (void)in_sizes; (void)n_in; (void)out_size; (void)ws_size;
  const float* x    = (const float*)d_in[0];
  const float* pos  = (const float*)d_in[1];
  const int*   ei   = (const int*)d_in[2];
  const int*   pei  = (const int*)d_in[3];
  const float* ppos = (const float*)d_in[4];
  const int*   keep = (const int*)d_in[5];
  const float* l0w  = (const float*)d_in[6];
  const float* l0b  = (const float*)d_in[7];
  const float* l1w  = (const float*)d_in[8];
  const float* l1b  = (const float*)d_in[9];
  const float* c0w0 = (const float*)d_in[10];
  const float* c0b0 = (const float*)d_in[11];
  const float* c0w1 = (const float*)d_in[12];
  const float* c0b1 = (const float*)d_in[13];
  const float* c0w2 = (const float*)d_in[14];
  const float* c0b2 = (const float*)d_in[15];
  const float* c0bias = (const float*)d_in[16];
  const float* c1w0 = (const float*)d_in[17];
  const float* c1b0 = (const float*)d_in[18];
  const float* c1w1 = (const float*)d_in[19];
  const float* c1b1 = (const float*)d_in[20];
  const float* c1w2 = (const float*)d_in[21];
  const float* c1b2 = (const float*)d_in[22];
  const float* c1bias = (const float*)d_in[23];
  float* outp = (float*)d_out;

  char* p = (char*)d_ws;
  auto carve = [&](size_t bytes) -> char* {
    char* r = p;
    p += (bytes + 255) & ~(size_t)255;
    return r;
  };
  float* hc0  = (float*)carve((size_t)N0C * HC * 4);
  float* tN0  = (float*)carve((size_t)N0C * HC * 4);
  float* dN0  = (float*)carve((size_t)N0C * 4);
  float* tN1  = (float*)carve((size_t)N1C * HC * 4);
  float* dN1  = (float*)carve((size_t)N1C * 4);
  _Float16* bC0  = (_Float16*)carve(4096 * 2);
  _Float16* bS0  = (_Float16*)carve(4096 * 2);
  _Float16* bC1  = (_Float16*)carve(4096 * 2);
  _Float16* bS1  = (_Float16*)carve(4096 * 2);
  _Float16* w1f0 = (_Float16*)carve(4096 * 2);
  _Float16* w1f1 = (_Float16*)carve(4096 * 2);
  int* cnt  = (int*)carve((size_t)(N0C + N1C) * 4);  // cnt+fill contiguous
  int* fill = (int*)carve((size_t)(N0C + N1C) * 4);
  int* rp0 = (int*)carve((size_t)(N0C + 1) * 4);
  int* rp1 = (int*)carve((size_t)(N1C + 1) * 4);
  int* eidx0 = (int*)carve((size_t)E0T * 4);
  int* eidx1 = (int*)carve((size_t)E1T * 4);
  int* inv0  = (int*)carve((size_t)E0T * 4);
  int* inv1  = (int*)carve((size_t)E1T * 4);
  float* msg = (float*)carve((size_t)E0T * HC * 4);  // reused for level 1

  hipMemsetAsync(cnt, 0, (size_t)(N0C + N1C) * 4 * 2, stream);

  k_prep<<<256 + 180, 256, 0, stream>>>(x, l0w, l0b, pos, c0w2, c0b2,
                                        c0w0, c1w0, c0w1, c1w1, ei, pei,
                                        bC0, bS0, bC1, bS1, w1f0, w1f1,
                                        cnt, tN0, dN0);
  k_scan<<<2, 1024, 0, stream>>>(cnt, rp0, rp1);
  k_scatter<<<(E0T + E1T + 255) / 256, 256, 0, stream>>>(ei, pei, rp0, rp1, fill,
                                                         eidx0, eidx1, inv0, inv1);
  k_conv<<<1536, 256, 0, stream>>>(ei, E0C, E0T, pos, tN0, dN0, c0w0, c0b0,
                                   bC0, bS0, w1f0, c0b1, inv0, msg);
  k_reduce0<<<N0C / 4, 256, 0, stream>>>(msg, rp0, c0bias, hc0);
  k_pool1<<<N1C / 4, 256, 0, stream>>>(hc0, eidx0, rp0, ei, keep, ppos,
                                       c1w2, c1b2, tN1, dN1);
  k_conv<<<768, 256, 0, stream>>>(pei, E1C, E1T, ppos, tN1, dN1, c1w0, c1b0,
                                  bC1, bS1, w1f1, c1b1, inv1, msg);
  k_reduce1f<<<N1C / 4, 256, 0, stream>>>(msg, rp1, c1bias, l1w, l1b, outp);
}